// Round 4
// baseline (249.123 us; speedup 1.0000x reference)
//
#include <hip/hip_runtime.h>
#include <math.h>

// Spectral_Filter_Transform: per-channel rfft -> keep top-16 |X| bins -> irfft
// (= sum of 16 cosines) -> flip-pad 12 -> 25-tap periodic-Hamming average.
//
// 2-kernel pipeline (transpose ELIMINATED):
//   K2: per-channel radix-16^3 register FFT reading x DIRECTLY with strided
//       loads (XCD-chunked block swizzle makes the 16 channels sharing each
//       64B line co-resident on one XCD -> L2 serves the reuse) + register
//       top-k; emits a compact 88-float RECORD per channel into ws (1.4 MB).
//   K3: reconstruction: stages 64 hot floats/record in LDS (33 KB -> 4
//       blocks/CU, single dispatch round), Chebyshev recurrence per
//       (t,channel), writes out directly in (B,T,F) (coalesced).
// Fallback single-kernel version if ws is too small.

#define NN     4096
#define LOGN   12
#define NT     256
#define EPT    16      // NN / NT
#define KTOP   16
#define WSZ    25
#define HALFW  12
#define FDIM   128
#define BATCH  32
#define RECL   88      // record: 16 vr' | 16 vi' | 16 cd2 | 16 fj | 24 delta
#define TT     128     // K3 time-tile per block
#define TWO_PI 6.283185307179586f

// skew: spreads power-of-2 LDS strides across banks; preserves float4 groups.
__device__ __forceinline__ int swz(int a) { return a + (a >> 5); }

#define CMUL(r, i, wr_, wi_) { float _r = (r); (r) = _r * (wr_) - (i) * (wi_); (i) = _r * (wi_) + (i) * (wr_); }
#define MULNI(r, i)          { float _r = (r); (r) = (i); (i) = -_r; }   // *(-i)

// cos/sin of +2*pi*ph/NN via the HW transcendental units.
// v_sin_f32 / v_cos_f32 take input in REVOLUTIONS; ph in [0, NN) -> rev in [0,1).
// ~1-2 ulp: used only for reconstruction phase seeds (never for the FFT or
// the top-k selection path).
__device__ __forceinline__ void cs_phase(int ph, float& c, float& s)
{
    const float rev = (float)ph * (1.0f / (float)NN);
    s = __builtin_amdgcn_sinf(rev);
    c = __builtin_amdgcn_cosf(rev);
}

// 16-point forward DFT (W16 = e^{-2pi i/16}) fully in registers, natural order.
__device__ __forceinline__ void dft16(float (&zr)[16], float (&zi)[16])
{
    const float C1 = 0.92387953251128674f;   // cos(pi/8)
    const float S1 = 0.38268343236508978f;   // sin(pi/8)
    const float R2 = 0.70710678118654752f;   // sqrt(2)/2
    float yr[16], yi[16];
    #pragma unroll
    for (int n2 = 0; n2 < 4; ++n2) {
        float ar = zr[n2],      ai = zi[n2];
        float br = zr[4 + n2],  bi = zi[4 + n2];
        float cr = zr[8 + n2],  ci = zi[8 + n2];
        float dr = zr[12 + n2], di = zi[12 + n2];
        float t0r = ar + cr, t0i = ai + ci;
        float t1r = ar - cr, t1i = ai - ci;
        float t2r = br + dr, t2i = bi + di;
        float t3r = br - dr, t3i = bi - di;
        yr[n2]      = t0r + t2r;  yi[n2]      = t0i + t2i;   // k1=0
        yr[4 + n2]  = t1r + t3i;  yi[4 + n2]  = t1i - t3r;   // k1=1  (t1 - i t3)
        yr[8 + n2]  = t0r - t2r;  yi[8 + n2]  = t0i - t2i;   // k1=2
        yr[12 + n2] = t1r - t3i;  yi[12 + n2] = t1i + t3r;   // k1=3  (t1 + i t3)
    }
    // step B: y[k1*4+n2] *= W16^{k1*n2}
    CMUL(yr[5],  yi[5],  C1, -S1);    // W^1
    CMUL(yr[6],  yi[6],  R2, -R2);    // W^2
    CMUL(yr[7],  yi[7],  S1, -C1);    // W^3
    CMUL(yr[9],  yi[9],  R2, -R2);    // W^2
    MULNI(yr[10], yi[10]);            // W^4 = -i
    CMUL(yr[11], yi[11], -R2, -R2);   // W^6
    CMUL(yr[13], yi[13], S1, -C1);    // W^3
    CMUL(yr[14], yi[14], -R2, -R2);   // W^6
    CMUL(yr[15], yi[15], -C1, S1);    // W^9
    // step C: radix-4 over n2 within each k1 row; X[4k2+k1] (natural order)
    #pragma unroll
    for (int k1 = 0; k1 < 4; ++k1) {
        float ar = yr[k1 * 4 + 0], ai = yi[k1 * 4 + 0];
        float br = yr[k1 * 4 + 1], bi = yi[k1 * 4 + 1];
        float cr = yr[k1 * 4 + 2], ci = yi[k1 * 4 + 2];
        float dr = yr[k1 * 4 + 3], di = yi[k1 * 4 + 3];
        float t0r = ar + cr, t0i = ai + ci;
        float t1r = ar - cr, t1i = ai - ci;
        float t2r = br + dr, t2i = bi + di;
        float t3r = br - dr, t3i = bi - di;
        zr[k1]      = t0r + t2r;  zi[k1]      = t0i + t2i;
        zr[4 + k1]  = t1r + t3i;  zi[4 + k1]  = t1i - t3r;
        zr[8 + k1]  = t0r - t2r;  zi[8 + k1]  = t0i - t2i;
        zr[12 + k1] = t1r - t3i;  zi[12 + k1] = t1i + t3r;
    }
}

// -------------------------------------------------- main analysis kernel (K2)
__global__ __launch_bounds__(NT, 4)
void spectral_fft_kernel(const float* __restrict__ x, float* __restrict__ ws)
{
    __shared__ float s_re[NN + (NN >> 5)];
    __shared__ float s_im[NN + (NN >> 5)];
    __shared__ float s_w[WSZ];
    __shared__ float s_wsum;
    __shared__ float s_rv[8];
    __shared__ int   s_rk[8];
    __shared__ int   s_kf[KTOP];
    __shared__ float s_kr[KTOP];
    __shared__ float s_ki[KTOP];
    __shared__ float s_vr[KTOP];             // bins premultiplied by window response
    __shared__ float s_vi[KTOP];
    __shared__ float s_cd2[KTOP];            // 2*cos(2π f/N) per bin
    __shared__ float s_edge[2 * HALFW];      // true xf[0..11], xf[N-12..N-1]
    __shared__ float s_dl[2 * HALFW];        // flip-pad deltas (already / wsum)

    const int tid = threadIdx.x;

    // XCD-chunked bijective swizzle: HW round-robins blockIdx across the 8
    // XCDs; remap so each XCD owns 512 CONSECUTIVE logical channels -> the 16
    // channels sharing every 64B line of x are co-resident on one XCD and
    // the strided gather below is served from that XCD's L2 (working set
    // ~2MB < 4MB) instead of refetching lines 16x from HBM/L3.
    const int p  = blockIdx.x;
    const int wg = ((p & 7) << 9) + (p >> 3);          // grid = 4096 = 8*512
    const int b  = wg >> 7;
    const int f  = wg & (FDIM - 1);
    const float* xc = x + (size_t)b * NN * FDIM + f;

    if (tid < WSZ)
        s_w[tid] = 0.54f - 0.46f * cosf(TWO_PI * (float)tid / (float)WSZ);

    // strided channel gather (stride 512B): issue all 16 loads up front.
    float zr[16], zi[16];
    #pragma unroll
    for (int r = 0; r < 16; ++r) { zr[r] = xc[(tid + (r << 8)) * FDIM]; zi[r] = 0.0f; }

    // ---- stage 0 (L=4096): 16-pt DFT in registers
    dft16(zr, zi);

    if (tid == 0) {                  // wave 0 wrote s_w above; wave-coherent read
        float a = 0.0f;
        for (int i = 0; i < WSZ; ++i) a += s_w[i];
        s_wsum = a;
    }

    {   // twiddle W_4096^{tid*u} via seed + rotation; scatter to LDS at tid+256u
        float sn, cs;
        sincosf(-TWO_PI * (float)tid / (float)NN, &sn, &cs);
        float dr = cs, di = sn;
        float wr = dr, wi = di;
        #pragma unroll
        for (int u = 1; u < 16; ++u) {
            CMUL(zr[u], zi[u], wr, wi);
            float nr = wr * dr - wi * di; wi = wr * di + wi * dr; wr = nr;
        }
        #pragma unroll
        for (int u = 0; u < 16; ++u) {
            int a = swz(tid + (u << 8));
            s_re[a] = zr[u]; s_im[a] = zi[u];
        }
    }
    __syncthreads();

    {   // ---- stage 1 (L=256): segment g=tid>>4, offset p=tid&15
        const int pp = tid & 15;
        const int b0 = ((tid >> 4) << 8) + pp;
        #pragma unroll
        for (int r = 0; r < 16; ++r) {
            int a = swz(b0 + (r << 4));
            zr[r] = s_re[a]; zi[r] = s_im[a];
        }
        dft16(zr, zi);
        float sn, cs;
        sincosf(-TWO_PI * (float)(pp << 4) / (float)NN, &sn, &cs);
        float dr = cs, di = sn;
        float wr = dr, wi = di;
        #pragma unroll
        for (int u = 1; u < 16; ++u) {
            CMUL(zr[u], zi[u], wr, wi);
            float nr = wr * dr - wi * di; wi = wr * di + wi * dr; wr = nr;
        }
        #pragma unroll
        for (int u = 0; u < 16; ++u) {
            int a = swz(b0 + (u << 4));
            s_re[a] = zr[u]; s_im[a] = zi[u];
        }
    }
    __syncthreads();

    {   // ---- stage 2 (L=16): contiguous 16, no twiddles; results stay in regs
        #pragma unroll
        for (int r = 0; r < 16; ++r) {
            int a = swz((tid << 4) + r);
            zr[r] = s_re[a]; zi[r] = s_im[a];
        }
        dft16(zr, zi);
    }

    // thread tid's result u is true bin f = 256*u + fbase, fbase = nibbleswap(tid).
    // Valid rfft bins: u<8 always; u==8 only for tid==0 (f=2048=Nyquist).
    const int fbase = ((tid & 15) << 4) | (tid >> 4);
    float mg[9];
    float lmax = -1.0f; int lk = 0x7fffffff;
    #pragma unroll
    for (int u = 0; u < 9; ++u) {
        float v = zr[u] * zr[u] + zi[u] * zi[u];
        if (u == 8 && fbase != 0) v = -1.0f;
        mg[u] = v;
        if (v > lmax) { lmax = v; lk = (u << 8) + fbase; }  // ascending f: > keeps lowest
    }

    // 16 rounds of block argmax over 256 cached per-thread maxima
    for (int r = 0; r < KTOP; ++r) {
        float bv = lmax; int bk = lk;
        #pragma unroll
        for (int off = 32; off > 0; off >>= 1) {
            float ov = __shfl_down(bv, off);
            int   ok = __shfl_down(bk, off);
            if (ov > bv || (ov == bv && ok < bk)) { bv = ov; bk = ok; }
        }
        const int buf = (r & 1) << 2;
        if ((tid & 63) == 0) { s_rv[buf + (tid >> 6)] = bv; s_rk[buf + (tid >> 6)] = bk; }
        __syncthreads();
        bv = s_rv[buf]; bk = s_rk[buf];
        #pragma unroll
        for (int w2 = 1; w2 < 4; ++w2) {
            float ov = s_rv[buf + w2]; int ok = s_rk[buf + w2];
            if (ov > bv || (ov == bv && ok < bk)) { bv = ov; bk = ok; }
        }
        if (lmax == bv && lk == bk) {      // unique winner thread
            const int uw = bk >> 8;
            s_kf[r] = bk;                  // bk == u*256 + fbase == true bin f
            #pragma unroll
            for (int u2 = 0; u2 < 9; ++u2) {       // predicated selects, no dyn index
                if (u2 == uw) { s_kr[r] = zr[u2]; s_ki[r] = zi[u2]; mg[u2] = -1.0f; }
            }
            lmax = -1.0f; lk = 0x7fffffff;
            #pragma unroll
            for (int u2 = 0; u2 < 9; ++u2) {
                float v = mg[u2];
                if (v > lmax) { lmax = v; lk = (u2 << 8) + fbase; }
            }
        }
    }
    __syncthreads();    // s_kf/s_kr/s_ki of the last round visible to all

    // ---- record prep (divergent, two different waves, both cheap):
    // wave 0 (tid<24): true edge samples xf[0..11] and xf[N-12..N-1] from raw bins
    //   (the fused reconstruction uses PERIODIC extension; the reference uses
    //    FLIP padding — they differ only in these 24 samples).
    // wave 1 (tid 64..79): fold the 25-tap Hamming frequency response
    //   H(f) = sum_i w_i e^{i 2π f (i-12)/N} into each bin:
    //   V' = V * sc * H(f) / (N * sum w)  — interior outputs = Re(V' e^{iθ_t}).
    if (tid < 2 * HALFW) {
        const int te = (tid < HALFW) ? tid : (NN - 2 * HALFW + tid);
        float a = 0.0f;
        for (int r = 0; r < KTOP; ++r) {
            const int fj = s_kf[r];
            float vr = s_kr[r], vi = s_ki[r];
            if (fj == 0 || fj == NN / 2) { vi = 0.0f; }
            else { vr *= 2.0f; vi *= 2.0f; }
            float c, s;
            cs_phase((fj * te) & (NN - 1), c, s);
            a += vr * c - vi * s;
        }
        s_edge[tid] = a * (1.0f / (float)NN);
    }
    if (tid >= 64 && tid < 64 + KTOP) {
        const int r = tid - 64;
        const int fj = s_kf[r];
        float vr = s_kr[r], vi = s_ki[r];
        float sc;
        if (fj == 0 || fj == NN / 2) { vi = 0.0f; sc = 1.0f; }
        else                         { sc = 2.0f; }
        float cr, ci, dc, ds;
        cs_phase((-HALFW * fj) & (NN - 1), cr, ci);   // e^{-i 12 δ}
        cs_phase(fj, dc, ds);                          // e^{+i δ}
        float hr = 0.0f, hi = 0.0f;
        for (int i = 0; i < WSZ; ++i) {
            const float wv = s_w[i];
            hr += wv * cr; hi += wv * ci;
            float nc = cr * dc - ci * ds;
            ci = ci * dc + cr * ds;
            cr = nc;
        }
        const float scale = sc / ((float)NN * s_wsum);
        s_vr[r]  = (vr * hr - vi * hi) * scale;
        s_vi[r]  = (vr * hi + vi * hr) * scale;
        s_cd2[r] = dc + dc;
    }
    __syncthreads();

    // ---- flip-pad edge deltas (one thread; 24 values, tiny)
    if (tid == 0) {
        const float rinv = 1.0f / s_wsum;
        for (int t = 0; t < HALFW; ++t) {
            float d = 0.0f;
            for (int i = 0; t + i < HALFW; ++i)
                d += s_w[i] * (s_edge[HALFW - 1 - t - i] - s_edge[HALFW + t + i]);
            s_dl[t] = d * rinv;
        }
        for (int j = 0; j < HALFW; ++j) {
            float d = 0.0f;
            for (int i = 2 * HALFW - j; i < WSZ; ++i)
                d += s_w[i] * (s_edge[4 * HALFW - 1 - j - i] - s_edge[j + i - 2 * HALFW]);
            s_dl[HALFW + j] = d * rinv;
        }
    }
    __syncthreads();

    // ---- write the compact 88-float record for this channel
    if (tid < RECL) {
        float v;
        if      (tid < 16) v = s_vr[tid];
        else if (tid < 32) v = s_vi[tid - 16];
        else if (tid < 48) v = s_cd2[tid - 32];
        else if (tid < 64) v = (float)s_kf[tid - 48];   // f <= 2048: exact in fp32
        else               v = s_dl[tid - 64];
        ws[(size_t)wg * RECL + tid] = v;
    }
}

// ---------------------------------------------- reconstruction kernel (K3)
// Block = (t-tile of TT=128, batch b). Stages the 64 HOT floats of all 128
// channel records in LDS (33.3 KB -> 4 blocks/CU, all 1024 blocks co-resident
// in ONE dispatch round). Each thread reconstructs 4 channels x 16 t via the
// Chebyshev recurrence and writes out directly in (B,T,F) layout.
// Edge blocks read their 24 flip-pad deltas straight from global (L3-hot).
__global__ __launch_bounds__(NT, 4)
void spectral_recon_kernel(const float* __restrict__ ws, float* __restrict__ out)
{
    __shared__ float s_c[FDIM * 65];   // stride 65 (odd): conflict-free lanes

    const int tid = threadIdx.x;
    const int tb  = blockIdx.x * TT;
    const int b   = blockIdx.y;
    const int chB = b * FDIM;

    #pragma unroll
    for (int k = 0; k < (FDIM * 64) / NT; ++k) {     // 32 iters, exact
        int idx = tid + (k << 8);
        int ch  = idx >> 6;
        int j   = idx & 63;
        s_c[ch * 65 + j] = ws[(size_t)(chB + ch) * RECL + j];
    }
    __syncthreads();

    const int m  = tid & 31;        // channel within group of 32
    const int tq = tid >> 5;        // 0..7
    const int t0 = tb + tq * 16;

    float acc[4][16];
    #pragma unroll
    for (int c = 0; c < 4; ++c)
        #pragma unroll
        for (int i = 0; i < 16; ++i) acc[c][i] = 0.0f;

    for (int r = 0; r < KTOP; ++r) {
        #pragma unroll
        for (int c = 0; c < 4; ++c) {
            const float* rec = &s_c[(c * 32 + m) * 65];
            const float vr  = rec[r];
            const float vi  = rec[16 + r];
            const float cd2 = rec[32 + r];
            const int   fj  = (int)rec[48 + r];
            const int   p0  = (fj * t0) & (NN - 1);
            float c0, s0, cm, sm;
            cs_phase(p0, c0, s0);
            cs_phase((p0 - fj) & (NN - 1), cm, sm);
            float g1 = vr * c0 - vi * s0;     // g at t0
            float g0 = vr * cm - vi * sm;     // g at t0-1
            #pragma unroll
            for (int i = 0; i < 16; ++i) {
                acc[c][i] += g1;
                const float gn = __builtin_fmaf(cd2, g1, -g0);
                g0 = g1; g1 = gn;
            }
        }
    }

    #pragma unroll
    for (int c = 0; c < 4; ++c) {
        const int ch = c * 32 + m;
        if (tb == 0 && tq == 0) {             // t = 0..11: flip-pad delta
            #pragma unroll
            for (int i = 0; i < HALFW; ++i)
                acc[c][i] += ws[(size_t)(chB + ch) * RECL + 64 + i];
        }
        if (tb == NN - TT && tq == 7) {       // t = 4084..4095
            #pragma unroll
            for (int i = 4; i < 16; ++i)
                acc[c][i] += ws[(size_t)(chB + ch) * RECL + 76 + (i - 4)];
        }
        const size_t obase = ((size_t)b * NN + t0) * FDIM + ch;
        #pragma unroll
        for (int i = 0; i < 16; ++i)
            out[obase + (size_t)i * FDIM] = acc[c][i];
    }
}

// ---------------------------------------------------------------- fallback
__global__ __launch_bounds__(NT, 3)
void spectral_filter_fallback(const float* __restrict__ x, float* __restrict__ out)
{
    __shared__ float s_re[NN + (NN >> 5)];
    __shared__ float s_im[NN];
    __shared__ float s_tw[NN];
    __shared__ float s_w[WSZ];
    __shared__ float s_wsum;
    __shared__ float s_rv[NT / 64];
    __shared__ int   s_ri[NT / 64];
    __shared__ int   s_kf[KTOP];
    __shared__ float s_kr[KTOP];
    __shared__ float s_ki[KTOP];

    const int tid = threadIdx.x;
    const int c   = blockIdx.x;
    const int b   = c >> 7;
    const int f   = c & (FDIM - 1);
    const size_t base = (size_t)b * NN * FDIM + f;

    if (tid < WSZ)
        s_w[tid] = 0.54f - 0.46f * cosf(TWO_PI * (float)tid / (float)WSZ);

    for (int i = tid; i < NN / 2; i += NT) {
        float sn, cs;
        sincosf(-TWO_PI * (float)i / (float)NN, &sn, &cs);
        s_tw[i]          = cs;
        s_tw[i + NN / 2] = sn;
    }

    #pragma unroll
    for (int i = 0; i < EPT; ++i) {
        int j = tid + i * NT;
        int t = (int)(__brev((unsigned)j) >> (32 - LOGN));
        s_re[j] = x[base + (size_t)t * FDIM];
        s_im[j] = 0.0f;
    }
    __syncthreads();

    if (tid == 0) {
        float a = 0.0f;
        for (int i = 0; i < WSZ; ++i) a += s_w[i];
        s_wsum = a;
    }

    for (int s = 1; s <= LOGN; ++s) {
        const int half = 1 << (s - 1);
        const int tsh  = LOGN - s;
        #pragma unroll
        for (int i = 0; i < EPT / 2; ++i) {
            int j  = tid + i * NT;
            int p  = j & (half - 1);
            int i0 = ((j >> (s - 1)) << s) + p;
            int i1 = i0 + half;
            int q  = p << tsh;
            float wr = s_tw[q], wi = s_tw[q + NN / 2];
            float ar = s_re[i0], ai = s_im[i0];
            float br = s_re[i1], bi = s_im[i1];
            float tr = br * wr - bi * wi;
            float ti = br * wi + bi * wr;
            s_re[i0] = ar + tr;  s_im[i0] = ai + ti;
            s_re[i1] = ar - tr;  s_im[i1] = ai - ti;
        }
        __syncthreads();
    }

    for (int i = tid; i < NN / 2 + 1; i += NT) {
        float rr = s_re[i], ii = s_im[i];
        s_tw[i] = rr * rr + ii * ii;
    }
    __syncthreads();

    for (int r = 0; r < KTOP; ++r) {
        float best = -1.0f; int bidx = 0x7fffffff;
        for (int i = tid; i < NN / 2 + 1; i += NT) {
            float v = s_tw[i];
            if (v > best) { best = v; bidx = i; }
        }
        #pragma unroll
        for (int off = 32; off > 0; off >>= 1) {
            float ov = __shfl_down(best, off);
            int   oi = __shfl_down(bidx, off);
            if (ov > best || (ov == best && oi < bidx)) { best = ov; bidx = oi; }
        }
        const int wid = tid >> 6;
        if ((tid & 63) == 0) { s_rv[wid] = best; s_ri[wid] = bidx; }
        __syncthreads();
        if (tid == 0) {
            float bv = s_rv[0]; int bx = s_ri[0];
            #pragma unroll
            for (int w2 = 1; w2 < NT / 64; ++w2) {
                float ov = s_rv[w2]; int oi = s_ri[w2];
                if (ov > bv || (ov == bv && oi < bx)) { bv = ov; bx = oi; }
            }
            s_kf[r] = bx;
            s_kr[r] = s_re[bx];
            s_ki[r] = s_im[bx];
            s_tw[bx] = -1.0f;
        }
        __syncthreads();
    }

    const int t0 = tid * EPT;
    float xf[EPT];
    #pragma unroll
    for (int i = 0; i < EPT; ++i) xf[i] = 0.0f;

    for (int r = 0; r < KTOP; ++r) {
        const int fj = s_kf[r];
        float vr = s_kr[r], vi = s_ki[r];
        float sc = 2.0f;
        if (fj == 0 || fj == NN / 2) { sc = 1.0f; vi = 0.0f; }
        vr *= sc; vi *= sc;
        const int ph0 = (fj * t0) & (NN - 1);
        float c0, s0, dc, ds;
        sincosf((float)ph0 * (TWO_PI / (float)NN), &s0, &c0);
        sincosf((float)fj  * (TWO_PI / (float)NN), &ds, &dc);
        float cr = c0, ci = s0;
        #pragma unroll
        for (int i = 0; i < EPT; ++i) {
            xf[i] += vr * cr - vi * ci;
            float nc = cr * dc - ci * ds;
            ci = ci * dc + cr * ds;
            cr = nc;
        }
    }
    __syncthreads();

    #pragma unroll
    for (int i = 0; i < EPT; ++i)
        s_re[swz(t0 + i)] = xf[i] * (1.0f / (float)NN);
    __syncthreads();

    float win[EPT + WSZ - 1];
    #pragma unroll
    for (int i = 0; i < EPT + WSZ - 1; ++i) {
        int a = t0 + i - HALFW;
        if (a < 0)        a = -1 - a;
        else if (a >= NN) a = 2 * NN - 1 - a;
        win[i] = s_re[swz(a)];
    }

    const float rinv = 1.0f / s_wsum;
    float acc[EPT];
    #pragma unroll
    for (int t = 0; t < EPT; ++t) acc[t] = 0.0f;
    #pragma unroll
    for (int i = 0; i < WSZ; ++i) {
        const float wv = s_w[i];
        #pragma unroll
        for (int t = 0; t < EPT; ++t) acc[t] += win[t + i] * wv;
    }
    #pragma unroll
    for (int t = 0; t < EPT; ++t)
        out[base + (size_t)(t0 + t) * FDIM] = acc[t] * rinv;
}

extern "C" void kernel_launch(void* const* d_in, const int* in_sizes, int n_in,
                              void* d_out, int out_size, void* d_ws, size_t ws_size,
                              hipStream_t stream)
{
    const float* x = (const float*)d_in[0];
    float* out = (float*)d_out;
    const size_t need = (size_t)BATCH * FDIM * RECL * sizeof(float);
    if (ws_size >= need) {
        float* ws = (float*)d_ws;
        spectral_fft_kernel<<<dim3(BATCH * FDIM), NT, 0, stream>>>(x, ws);
        spectral_recon_kernel<<<dim3(NN / TT, BATCH), NT, 0, stream>>>(ws, out);
    } else {
        spectral_filter_fallback<<<dim3(BATCH * FDIM), NT, 0, stream>>>(x, out);
    }
}

// Round 6
// 227.429 us; speedup vs baseline: 1.0954x; 1.0954x over previous
//
#include <hip/hip_runtime.h>
#include <math.h>

// Spectral_Filter_Transform: per-channel rfft -> keep top-16 |X| bins -> irfft
// (= sum of 16 cosines) -> flip-pad 12 -> 25-tap periodic-Hamming average.
//
// 2-kernel pipeline (transpose-free):
//   K2: per-channel radix-16^3 register FFT reading x directly (XCD-chunked
//       swizzle for L2 reuse of the strided gather). Single 16.9 KB LDS
//       exchange buffer (RE pass then IM pass) -> 18.6 KB/block -> 6+
//       blocks/CU for latency hiding. Top-k = per-wave shuffle top-16 +
//       single-wave merge (2 block barriers instead of 16). Emits an
//       88-float RECORD per channel into ws (1.4 MB).
//   K3: reconstruction: channel-outer Chebyshev recurrence (low VGPR, no
//       spill), writes out directly in (B,T,F) layout (coalesced).
// Fallback single-kernel version if ws is too small.

#define NN     4096
#define LOGN   12
#define NT     256
#define EPT    16      // NN / NT
#define KTOP   16
#define WSZ    25
#define HALFW  12
#define FDIM   128
#define BATCH  32
#define RECL   88      // record: 16 vr' | 16 vi' | 16 cd2 | 16 fj | 24 delta
#define TT     128     // K3 time-tile per block
#define TWO_PI 6.283185307179586f

// skew: spreads power-of-2 LDS strides across banks; preserves float4 groups.
__device__ __forceinline__ int swz(int a) { return a + (a >> 5); }

#define CMUL(r, i, wr_, wi_) { float _r = (r); (r) = _r * (wr_) - (i) * (wi_); (i) = _r * (wi_) + (i) * (wr_); }
#define MULNI(r, i)          { float _r = (r); (r) = (i); (i) = -_r; }   // *(-i)

// cos/sin of +2*pi*ph/NN via the HW transcendental units.
// v_sin_f32 / v_cos_f32 take input in REVOLUTIONS; ph in [0, NN) -> rev in [0,1).
// ~1-2 ulp: used only for reconstruction phase seeds (never for the FFT or
// the top-k selection path).
__device__ __forceinline__ void cs_phase(int ph, float& c, float& s)
{
    const float rev = (float)ph * (1.0f / (float)NN);
    s = __builtin_amdgcn_sinf(rev);
    c = __builtin_amdgcn_cosf(rev);
}

// 16-point forward DFT (W16 = e^{-2pi i/16}) fully in registers, natural order.
__device__ __forceinline__ void dft16(float (&zr)[16], float (&zi)[16])
{
    const float C1 = 0.92387953251128674f;   // cos(pi/8)
    const float S1 = 0.38268343236508978f;   // sin(pi/8)
    const float R2 = 0.70710678118654752f;   // sqrt(2)/2
    float yr[16], yi[16];
    #pragma unroll
    for (int n2 = 0; n2 < 4; ++n2) {
        float ar = zr[n2],      ai = zi[n2];
        float br = zr[4 + n2],  bi = zi[4 + n2];
        float cr = zr[8 + n2],  ci = zi[8 + n2];
        float dr = zr[12 + n2], di = zi[12 + n2];
        float t0r = ar + cr, t0i = ai + ci;
        float t1r = ar - cr, t1i = ai - ci;
        float t2r = br + dr, t2i = bi + di;
        float t3r = br - dr, t3i = bi - di;
        yr[n2]      = t0r + t2r;  yi[n2]      = t0i + t2i;   // k1=0
        yr[4 + n2]  = t1r + t3i;  yi[4 + n2]  = t1i - t3r;   // k1=1  (t1 - i t3)
        yr[8 + n2]  = t0r - t2r;  yi[8 + n2]  = t0i - t2i;   // k1=2
        yr[12 + n2] = t1r - t3i;  yi[12 + n2] = t1i + t3r;   // k1=3  (t1 + i t3)
    }
    // step B: y[k1*4+n2] *= W16^{k1*n2}
    CMUL(yr[5],  yi[5],  C1, -S1);    // W^1
    CMUL(yr[6],  yi[6],  R2, -R2);    // W^2
    CMUL(yr[7],  yi[7],  S1, -C1);    // W^3
    CMUL(yr[9],  yi[9],  R2, -R2);    // W^2
    MULNI(yr[10], yi[10]);            // W^4 = -i
    CMUL(yr[11], yi[11], -R2, -R2);   // W^6
    CMUL(yr[13], yi[13], S1, -C1);    // W^3
    CMUL(yr[14], yi[14], -R2, -R2);   // W^6
    CMUL(yr[15], yi[15], -C1, S1);    // W^9
    // step C: radix-4 over n2 within each k1 row; X[4k2+k1] (natural order)
    #pragma unroll
    for (int k1 = 0; k1 < 4; ++k1) {
        float ar = yr[k1 * 4 + 0], ai = yi[k1 * 4 + 0];
        float br = yr[k1 * 4 + 1], bi = yi[k1 * 4 + 1];
        float cr = yr[k1 * 4 + 2], ci = yi[k1 * 4 + 2];
        float dr = yr[k1 * 4 + 3], di = yi[k1 * 4 + 3];
        float t0r = ar + cr, t0i = ai + ci;
        float t1r = ar - cr, t1i = ai - ci;
        float t2r = br + dr, t2i = bi + di;
        float t3r = br - dr, t3i = bi - di;
        zr[k1]      = t0r + t2r;  zi[k1]      = t0i + t2i;
        zr[4 + k1]  = t1r + t3i;  zi[4 + k1]  = t1i - t3r;
        zr[8 + k1]  = t0r - t2r;  zi[8 + k1]  = t0i - t2i;
        zr[12 + k1] = t1r - t3i;  zi[12 + k1] = t1i + t3r;
    }
}

// -------------------------------------------------- main analysis kernel (K2)
__global__ __launch_bounds__(NT, 6)
void spectral_fft_kernel(const float* __restrict__ x, float* __restrict__ ws)
{
    __shared__ float s_x[NN + (NN >> 5)];    // single exchange buffer (16.9 KB)
    __shared__ float s_w[WSZ];
    __shared__ float s_wsum;
    __shared__ float s_cv[64];               // per-wave top-16 candidates
    __shared__ int   s_ck[64];
    __shared__ float s_cr[64];
    __shared__ float s_ci[64];
    __shared__ int   s_kf[KTOP];
    __shared__ float s_kr[KTOP];
    __shared__ float s_ki[KTOP];
    __shared__ float s_vr[KTOP];             // bins premultiplied by window response
    __shared__ float s_vi[KTOP];
    __shared__ float s_cd2[KTOP];            // 2*cos(2π f/N) per bin
    __shared__ float s_edge[2 * HALFW];      // true xf[0..11], xf[N-12..N-1]
    __shared__ float s_dl[2 * HALFW];        // flip-pad deltas (already / wsum)

    const int tid = threadIdx.x;

    // XCD-chunked bijective swizzle: each XCD owns 512 consecutive logical
    // channels so the 16 channels sharing each 64B line of x are co-resident
    // on one XCD (its L2 serves the strided gather's 16x line reuse).
    const int p  = blockIdx.x;
    const int wg = ((p & 7) << 9) + (p >> 3);          // grid = 4096 = 8*512
    const int b  = wg >> 7;
    const int f  = wg & (FDIM - 1);
    const float* xc = x + (size_t)b * NN * FDIM + f;

    if (tid < WSZ)
        s_w[tid] = 0.54f - 0.46f * cosf(TWO_PI * (float)tid / (float)WSZ);

    // strided channel gather (stride 512B): issue all 16 loads up front.
    float zr[16], zi[16];
    #pragma unroll
    for (int r = 0; r < 16; ++r) { zr[r] = xc[(tid + (r << 8)) * FDIM]; zi[r] = 0.0f; }

    // ---- stage 0 (L=4096): 16-pt DFT in registers
    dft16(zr, zi);

    if (tid == 0) {                  // wave 0 wrote s_w above; wave-coherent read
        float a = 0.0f;
        for (int i = 0; i < WSZ; ++i) a += s_w[i];
        s_wsum = a;
    }

    const int b0 = ((tid >> 4) << 8) + (tid & 15);

    {   // stage-0 twiddle W_4096^{tid*u} via seed + rotation
        float sn, cs;
        sincosf(-TWO_PI * (float)tid / (float)NN, &sn, &cs);
        float dr = cs, di = sn;
        float wr = dr, wi = di;
        #pragma unroll
        for (int u = 1; u < 16; ++u) {
            CMUL(zr[u], zi[u], wr, wi);
            float nr = wr * dr - wi * di; wi = wr * di + wi * dr; wr = nr;
        }
    }
    // ---- exchange 1 (scatter tid+256u -> gather b0+16r), RE then IM through s_x
    #pragma unroll
    for (int u = 0; u < 16; ++u) s_x[swz(tid + (u << 8))] = zr[u];
    __syncthreads();
    #pragma unroll
    for (int r = 0; r < 16; ++r) zr[r] = s_x[swz(b0 + (r << 4))];
    __syncthreads();
    #pragma unroll
    for (int u = 0; u < 16; ++u) s_x[swz(tid + (u << 8))] = zi[u];
    __syncthreads();
    #pragma unroll
    for (int r = 0; r < 16; ++r) zi[r] = s_x[swz(b0 + (r << 4))];

    // ---- stage 1 (L=256)
    dft16(zr, zi);
    {   // stage-1 twiddle
        const int pp = tid & 15;
        float sn, cs;
        sincosf(-TWO_PI * (float)(pp << 4) / (float)NN, &sn, &cs);
        float dr = cs, di = sn;
        float wr = dr, wi = di;
        #pragma unroll
        for (int u = 1; u < 16; ++u) {
            CMUL(zr[u], zi[u], wr, wi);
            float nr = wr * dr - wi * di; wi = wr * di + wi * dr; wr = nr;
        }
    }
    __syncthreads();    // all IM reads of exchange 1 complete before overwrite
    // ---- exchange 2 (scatter b0+16u -> gather 16*tid+r), RE then IM
    #pragma unroll
    for (int u = 0; u < 16; ++u) s_x[swz(b0 + (u << 4))] = zr[u];
    __syncthreads();
    #pragma unroll
    for (int r = 0; r < 16; ++r) zr[r] = s_x[swz((tid << 4) + r)];
    __syncthreads();
    #pragma unroll
    for (int u = 0; u < 16; ++u) s_x[swz(b0 + (u << 4))] = zi[u];
    __syncthreads();
    #pragma unroll
    for (int r = 0; r < 16; ++r) zi[r] = s_x[swz((tid << 4) + r)];

    // ---- stage 2 (L=16): contiguous, no twiddles
    dft16(zr, zi);

    // thread tid's result u is true bin f = 256*u + fbase, fbase = nibbleswap(tid).
    // Valid rfft bins: u<8 always; u==8 only for tid==0 (f=2048=Nyquist).
    const int fbase = ((tid & 15) << 4) | (tid >> 4);
    float mg[9];
    float lmax = -1.0f; int lk = 0x7fffffff;
    #pragma unroll
    for (int u = 0; u < 9; ++u) {
        float v = zr[u] * zr[u] + zi[u] * zi[u];
        if (u == 8 && fbase != 0) v = -1.0f;
        mg[u] = v;
        if (v > lmax) { lmax = v; lk = (u << 8) + fbase; }  // ascending f: > keeps lowest
    }

    // ---- per-wave top-16 (shuffle-only butterflies, NO block barriers).
    // Block top-16 is a subset of the union of the 4 per-wave top-16s.
    const int lane = tid & 63;
    const int wid  = tid >> 6;
    for (int r = 0; r < KTOP; ++r) {
        float bv = lmax; int bk = lk;
        #pragma unroll
        for (int off = 1; off < 64; off <<= 1) {
            float ov = __shfl_xor(bv, off);
            int   ok = __shfl_xor(bk, off);
            if (ov > bv || (ov == bv && ok < bk)) { bv = ov; bk = ok; }
        }
        if (lmax == bv && lk == bk) {      // unique winner thread (fbase unique)
            const int uw = bk >> 8;
            #pragma unroll
            for (int u2 = 0; u2 < 9; ++u2) {       // predicated, no dyn index
                if (u2 == uw) { s_cr[wid * 16 + r] = zr[u2]; s_ci[wid * 16 + r] = zi[u2]; mg[u2] = -1.0f; }
            }
            lmax = -1.0f; lk = 0x7fffffff;
            #pragma unroll
            for (int u2 = 0; u2 < 9; ++u2) {
                float v = mg[u2];
                if (v > lmax) { lmax = v; lk = (u2 << 8) + fbase; }
            }
        }
        if (lane == r) { s_cv[wid * 16 + r] = bv; s_ck[wid * 16 + r] = bk; }
    }
    __syncthreads();

    // ---- merge 64 candidates -> final top-16 on wave 0 (shuffle-only)
    if (tid < 64) {
        float cv = s_cv[tid]; int ck = s_ck[tid];
        float cr = s_cr[tid], ci = s_ci[tid];
        for (int r = 0; r < KTOP; ++r) {
            float bv = cv; int bk = ck;
            #pragma unroll
            for (int off = 1; off < 64; off <<= 1) {
                float ov = __shfl_xor(bv, off);
                int   ok = __shfl_xor(bk, off);
                if (ov > bv || (ov == bv && ok < bk)) { bv = ov; bk = ok; }
            }
            if (cv == bv && ck == bk) {    // unique owner (keys distinct)
                s_kf[r] = bk; s_kr[r] = cr; s_ki[r] = ci;
                cv = -1.0f; ck = 0x7fffffff;
            }
        }
    }
    __syncthreads();    // s_kf/s_kr/s_ki visible to all

    // ---- record prep (divergent, two different waves, both cheap):
    // wave 0 (tid<24): true edge samples xf[0..11] and xf[N-12..N-1] from raw bins
    //   (the fused reconstruction uses PERIODIC extension; the reference uses
    //    FLIP padding — they differ only in these 24 samples).
    // wave 1 (tid 64..79): fold the 25-tap Hamming frequency response
    //   H(f) = sum_i w_i e^{i 2π f (i-12)/N} into each bin:
    //   V' = V * sc * H(f) / (N * sum w)  — interior outputs = Re(V' e^{iθ_t}).
    if (tid < 2 * HALFW) {
        const int te = (tid < HALFW) ? tid : (NN - 2 * HALFW + tid);
        float a = 0.0f;
        for (int r = 0; r < KTOP; ++r) {
            const int fj = s_kf[r];
            float vr = s_kr[r], vi = s_ki[r];
            if (fj == 0 || fj == NN / 2) { vi = 0.0f; }
            else { vr *= 2.0f; vi *= 2.0f; }
            float c, s;
            cs_phase((fj * te) & (NN - 1), c, s);
            a += vr * c - vi * s;
        }
        s_edge[tid] = a * (1.0f / (float)NN);
    }
    if (tid >= 64 && tid < 64 + KTOP) {
        const int r = tid - 64;
        const int fj = s_kf[r];
        float vr = s_kr[r], vi = s_ki[r];
        float sc;
        if (fj == 0 || fj == NN / 2) { vi = 0.0f; sc = 1.0f; }
        else                         { sc = 2.0f; }
        float cr, ci, dc, ds;
        cs_phase((-HALFW * fj) & (NN - 1), cr, ci);   // e^{-i 12 δ}
        cs_phase(fj, dc, ds);                          // e^{+i δ}
        float hr = 0.0f, hi = 0.0f;
        for (int i = 0; i < WSZ; ++i) {
            const float wv = s_w[i];
            hr += wv * cr; hi += wv * ci;
            float nc = cr * dc - ci * ds;
            ci = ci * dc + cr * ds;
            cr = nc;
        }
        const float scale = sc / ((float)NN * s_wsum);
        s_vr[r]  = (vr * hr - vi * hi) * scale;
        s_vi[r]  = (vr * hi + vi * hr) * scale;
        s_cd2[r] = dc + dc;
    }
    __syncthreads();

    // ---- flip-pad edge deltas (one thread; 24 values, tiny)
    if (tid == 0) {
        const float rinv = 1.0f / s_wsum;
        for (int t = 0; t < HALFW; ++t) {
            float d = 0.0f;
            for (int i = 0; t + i < HALFW; ++i)
                d += s_w[i] * (s_edge[HALFW - 1 - t - i] - s_edge[HALFW + t + i]);
            s_dl[t] = d * rinv;
        }
        for (int j = 0; j < HALFW; ++j) {
            float d = 0.0f;
            for (int i = 2 * HALFW - j; i < WSZ; ++i)
                d += s_w[i] * (s_edge[4 * HALFW - 1 - j - i] - s_edge[j + i - 2 * HALFW]);
            s_dl[HALFW + j] = d * rinv;
        }
    }
    __syncthreads();

    // ---- write the compact 88-float record for this channel
    if (tid < RECL) {
        float v;
        if      (tid < 16) v = s_vr[tid];
        else if (tid < 32) v = s_vi[tid - 16];
        else if (tid < 48) v = s_cd2[tid - 32];
        else if (tid < 64) v = (float)s_kf[tid - 48];   // f <= 2048: exact in fp32
        else               v = s_dl[tid - 64];
        ws[(size_t)wg * RECL + tid] = v;
    }
}

// ---------------------------------------------- reconstruction kernel (K3)
// Block = (t-tile of TT=128, batch b). Stages the 64 HOT floats of all 128
// channel records in LDS (33.3 KB -> 4 blocks/CU, single dispatch round).
// CHANNEL-OUTER loop: acc[16] per channel keeps live VGPRs ~30 (no spill at
// the 128-reg cap of waves_per_eu=4). Each thread reconstructs 4 channels x
// 16 t and writes out directly in (B,T,F) layout.
__global__ __launch_bounds__(NT, 4)
void spectral_recon_kernel(const float* __restrict__ ws, float* __restrict__ out)
{
    __shared__ float s_c[FDIM * 65];   // stride 65 (odd): conflict-free lanes

    const int tid = threadIdx.x;
    const int tb  = blockIdx.x * TT;
    const int b   = blockIdx.y;
    const int chB = b * FDIM;

    #pragma unroll
    for (int k = 0; k < (FDIM * 64) / NT; ++k) {     // 32 iters, exact
        int idx = tid + (k << 8);
        int ch  = idx >> 6;
        int j   = idx & 63;
        s_c[ch * 65 + j] = ws[(size_t)(chB + ch) * RECL + j];
    }
    __syncthreads();

    const int m  = tid & 31;        // channel within group of 32
    const int tq = tid >> 5;        // 0..7
    const int t0 = tb + tq * 16;

    #pragma unroll 1
    for (int c = 0; c < 4; ++c) {
        const int ch = c * 32 + m;
        const float* rec = &s_c[ch * 65];

        float acc[16];
        #pragma unroll
        for (int i = 0; i < 16; ++i) acc[i] = 0.0f;

        for (int r = 0; r < KTOP; ++r) {
            const float vr  = rec[r];
            const float vi  = rec[16 + r];
            const float cd2 = rec[32 + r];
            const int   fj  = (int)rec[48 + r];
            const int   p0  = (fj * t0) & (NN - 1);
            float c0, s0, cm, sm;
            cs_phase(p0, c0, s0);
            cs_phase((p0 - fj) & (NN - 1), cm, sm);
            float g1 = vr * c0 - vi * s0;     // g at t0
            float g0 = vr * cm - vi * sm;     // g at t0-1
            #pragma unroll
            for (int i = 0; i < 16; ++i) {
                acc[i] += g1;
                const float gn = __builtin_fmaf(cd2, g1, -g0);
                g0 = g1; g1 = gn;
            }
        }

        if (tb == 0 && tq == 0) {             // t = 0..11: flip-pad delta
            #pragma unroll
            for (int i = 0; i < HALFW; ++i)
                acc[i] += ws[(size_t)(chB + ch) * RECL + 64 + i];
        }
        if (tb == NN - TT && tq == 7) {       // t = 4084..4095
            #pragma unroll
            for (int i = 4; i < 16; ++i)
                acc[i] += ws[(size_t)(chB + ch) * RECL + 76 + (i - 4)];
        }
        const size_t obase = ((size_t)b * NN + t0) * FDIM + ch;
        #pragma unroll
        for (int i = 0; i < 16; ++i)
            out[obase + (size_t)i * FDIM] = acc[i];
    }
}

// ---------------------------------------------------------------- fallback
__global__ __launch_bounds__(NT, 3)
void spectral_filter_fallback(const float* __restrict__ x, float* __restrict__ out)
{
    __shared__ float s_re[NN + (NN >> 5)];
    __shared__ float s_im[NN];
    __shared__ float s_tw[NN];
    __shared__ float s_w[WSZ];
    __shared__ float s_wsum;
    __shared__ float s_rv[NT / 64];
    __shared__ int   s_ri[NT / 64];
    __shared__ int   s_kf[KTOP];
    __shared__ float s_kr[KTOP];
    __shared__ float s_ki[KTOP];

    const int tid = threadIdx.x;
    const int c   = blockIdx.x;
    const int b   = c >> 7;
    const int f   = c & (FDIM - 1);
    const size_t base = (size_t)b * NN * FDIM + f;

    if (tid < WSZ)
        s_w[tid] = 0.54f - 0.46f * cosf(TWO_PI * (float)tid / (float)WSZ);

    for (int i = tid; i < NN / 2; i += NT) {
        float sn, cs;
        sincosf(-TWO_PI * (float)i / (float)NN, &sn, &cs);
        s_tw[i]          = cs;
        s_tw[i + NN / 2] = sn;
    }

    #pragma unroll
    for (int i = 0; i < EPT; ++i) {
        int j = tid + i * NT;
        int t = (int)(__brev((unsigned)j) >> (32 - LOGN));
        s_re[j] = x[base + (size_t)t * FDIM];
        s_im[j] = 0.0f;
    }
    __syncthreads();

    if (tid == 0) {
        float a = 0.0f;
        for (int i = 0; i < WSZ; ++i) a += s_w[i];
        s_wsum = a;
    }

    for (int s = 1; s <= LOGN; ++s) {
        const int half = 1 << (s - 1);
        const int tsh  = LOGN - s;
        #pragma unroll
        for (int i = 0; i < EPT / 2; ++i) {
            int j  = tid + i * NT;
            int p  = j & (half - 1);
            int i0 = ((j >> (s - 1)) << s) + p;
            int i1 = i0 + half;
            int q  = p << tsh;
            float wr = s_tw[q], wi = s_tw[q + NN / 2];
            float ar = s_re[i0], ai = s_im[i0];
            float br = s_re[i1], bi = s_im[i1];
            float tr = br * wr - bi * wi;
            float ti = br * wi + bi * wr;
            s_re[i0] = ar + tr;  s_im[i0] = ai + ti;
            s_re[i1] = ar - tr;  s_im[i1] = ai - ti;
        }
        __syncthreads();
    }

    for (int i = tid; i < NN / 2 + 1; i += NT) {
        float rr = s_re[i], ii = s_im[i];
        s_tw[i] = rr * rr + ii * ii;
    }
    __syncthreads();

    for (int r = 0; r < KTOP; ++r) {
        float best = -1.0f; int bidx = 0x7fffffff;
        for (int i = tid; i < NN / 2 + 1; i += NT) {
            float v = s_tw[i];
            if (v > best) { best = v; bidx = i; }
        }
        #pragma unroll
        for (int off = 32; off > 0; off >>= 1) {
            float ov = __shfl_down(best, off);
            int   oi = __shfl_down(bidx, off);
            if (ov > best || (ov == best && oi < bidx)) { best = ov; bidx = oi; }
        }
        const int wid = tid >> 6;
        if ((tid & 63) == 0) { s_rv[wid] = best; s_ri[wid] = bidx; }
        __syncthreads();
        if (tid == 0) {
            float bv = s_rv[0]; int bx = s_ri[0];
            #pragma unroll
            for (int w2 = 1; w2 < NT / 64; ++w2) {
                float ov = s_rv[w2]; int oi = s_ri[w2];
                if (ov > bv || (ov == bv && oi < bx)) { bv = ov; bx = oi; }
            }
            s_kf[r] = bx;
            s_kr[r] = s_re[bx];
            s_ki[r] = s_im[bx];
            s_tw[bx] = -1.0f;
        }
        __syncthreads();
    }

    const int t0 = tid * EPT;
    float xf[EPT];
    #pragma unroll
    for (int i = 0; i < EPT; ++i) xf[i] = 0.0f;

    for (int r = 0; r < KTOP; ++r) {
        const int fj = s_kf[r];
        float vr = s_kr[r], vi = s_ki[r];
        float sc = 2.0f;
        if (fj == 0 || fj == NN / 2) { sc = 1.0f; vi = 0.0f; }
        vr *= sc; vi *= sc;
        const int ph0 = (fj * t0) & (NN - 1);
        float c0, s0, dc, ds;
        sincosf((float)ph0 * (TWO_PI / (float)NN), &s0, &c0);
        sincosf((float)fj  * (TWO_PI / (float)NN), &ds, &dc);
        float cr = c0, ci = s0;
        #pragma unroll
        for (int i = 0; i < EPT; ++i) {
            xf[i] += vr * cr - vi * ci;
            float nc = cr * dc - ci * ds;
            ci = ci * dc + cr * ds;
            cr = nc;
        }
    }
    __syncthreads();

    #pragma unroll
    for (int i = 0; i < EPT; ++i)
        s_re[swz(t0 + i)] = xf[i] * (1.0f / (float)NN);
    __syncthreads();

    float win[EPT + WSZ - 1];
    #pragma unroll
    for (int i = 0; i < EPT + WSZ - 1; ++i) {
        int a = t0 + i - HALFW;
        if (a < 0)        a = -1 - a;
        else if (a >= NN) a = 2 * NN - 1 - a;
        win[i] = s_re[swz(a)];
    }

    const float rinv = 1.0f / s_wsum;
    float acc[EPT];
    #pragma unroll
    for (int t = 0; t < EPT; ++t) acc[t] = 0.0f;
    #pragma unroll
    for (int i = 0; i < WSZ; ++i) {
        const float wv = s_w[i];
        #pragma unroll
        for (int t = 0; t < EPT; ++t) acc[t] += win[t + i] * wv;
    }
    #pragma unroll
    for (int t = 0; t < EPT; ++t)
        out[base + (size_t)(t0 + t) * FDIM] = acc[t] * rinv;
}

extern "C" void kernel_launch(void* const* d_in, const int* in_sizes, int n_in,
                              void* d_out, int out_size, void* d_ws, size_t ws_size,
                              hipStream_t stream)
{
    const float* x = (const float*)d_in[0];
    float* out = (float*)d_out;
    const size_t need = (size_t)BATCH * FDIM * RECL * sizeof(float);
    if (ws_size >= need) {
        float* ws = (float*)d_ws;
        spectral_fft_kernel<<<dim3(BATCH * FDIM), NT, 0, stream>>>(x, ws);
        spectral_recon_kernel<<<dim3(NN / TT, BATCH), NT, 0, stream>>>(ws, out);
    } else {
        spectral_filter_fallback<<<dim3(BATCH * FDIM), NT, 0, stream>>>(x, out);
    }
}